// Round 8
// baseline (21365.466 us; speedup 1.0000x reference)
//
#include <hip/hip_runtime.h>

// Problem constants
#define BB    128   // batch
#define LL    2048  // seq len
#define FF    128   // input features
#define HH    256   // hidden
#define OO    128   // output
#define NTICK 5
#define GC    16    // chains per group
#define NGRP  8     // chain groups (prog[] entries)
#define NCG   4     // consumer blocks (2 groups each, phase-interleaved)
#define CH    4     // timesteps per ring chunk
#define DRING 128   // ring depth (timesteps)
#define NPS   8     // producer col-slices (96 cols each)
#define NPL   16    // producer chunk-lanes
#define MAXT  (LL + NTICK)
#define MAXCH ((MAXT + CH - 1) / CH)
#define RDY8  0x0101010101010101ULL

// Gate-column pre-scales folded into W/R/b/tick (bare v_exp_f32 in gate body):
//   ci cols: *2log2e ; ig/og cols: *-log2e.  c kept in ci-scaled units.
#define SC_CI  (2.8853900817779268f)
#define SC_GT  (-1.4426950408889634f)

typedef __attribute__((ext_vector_type(8))) _Float16 half8;
typedef __attribute__((ext_vector_type(2))) __fp16 fp16x2;
typedef __attribute__((ext_vector_type(4))) float f32x4;

union U64H4 { unsigned long long u; _Float16 h[4]; fp16x2 p[2]; };

__device__ __forceinline__ float fast_rcp(float x) { return __builtin_amdgcn_rcpf(x); }
__device__ __forceinline__ float fast_exp2(float x) { return __builtin_amdgcn_exp2f(x); }

__device__ __forceinline__ unsigned long long sysload_u64(const unsigned long long* p) {
  return __hip_atomic_load(p, __ATOMIC_RELAXED, __HIP_MEMORY_SCOPE_SYSTEM);
}
__device__ __forceinline__ void sysstore_u64(unsigned long long* p, unsigned long long v) {
  __hip_atomic_store(p, v, __ATOMIC_RELAXED, __HIP_MEMORY_SCOPE_SYSTEM);
}
__device__ __forceinline__ int sysload_i32(const int* p) {
  return __hip_atomic_load(p, __ATOMIC_RELAXED, __HIP_MEMORY_SCOPE_SYSTEM);
}
__device__ __forceinline__ void sysstore_i32(int* p, int v) {
  __hip_atomic_store(p, v, __ATOMIC_RELAXED, __HIP_MEMORY_SCOPE_SYSTEM);
}
__device__ __forceinline__ void sysstore_u8(unsigned char* p, unsigned char v) {
  __hip_atomic_store(p, v, __ATOMIC_RELAXED, __HIP_MEMORY_SCOPE_SYSTEM);
}

// Barrier with LDS-only drain: ring prefetch loads (vmcnt) stay in flight
// across the barrier; register dependency inserts the vmcnt wait at first use.
__device__ __forceinline__ void sync_lds_only() {
  asm volatile("s_waitcnt lgkmcnt(0)" ::: "memory");
  __builtin_amdgcn_s_barrier();
  asm volatile("" ::: "memory");
}

// Blocks 0..3: consumers. Each owns TWO independent 16-chain groups
// A (chains 32cg..+16) and B (+16), phase-interleaved so the MFMA pipe
// (group X's recurrent h@R) and the VALU/trans pipes (group Y's gates)
// overlap every phase instead of serializing:
//   phase1: MFMA_A(t) + gate_B(t-1)   | barrier
//   phase2: MFMA_B(t) + gate_A(t)     | barrier
// One barrier per group-step (was two), pipes overlapped.
// Blocks 4..131: producers (unchanged protocol; pre_x -> ring).
//
// MFMA layout: fragments loaded as B[k][n] (n=lane&15, k=quad*8+j); weight
// fragment in the A slot => lane nl reg r = pre[chain=nl][col=base+quad*4+r].
// Gate thread (m=tid>>5, q32=tid&31) owns dims {4*q32+128k}, bank-balanced.
extern "C" __global__ __launch_bounds__(512, 1)
void lstm_all(const float* __restrict__ x, const int* __restrict__ lens,
              const float* __restrict__ W, const float* __restrict__ R,
              const float* __restrict__ bvec, const float* __restrict__ btk,
              unsigned long long* ring, unsigned char* readyb,
              int* prog, float* __restrict__ h_final)
{
  const int tid  = threadIdx.x;
  const int lane = tid & 63;
  const int wv   = tid >> 6;
  const int quad = lane >> 4;
  const int nl   = lane & 15;
  const int bx   = blockIdx.x;

  __shared__ int lens_s[BB];
  if (tid < BB) lens_s[tid] = lens[tid];
  __syncthreads();

  if (bx < NCG) {
    // ======================= CONSUMER =======================
    const int cg = bx, cbase = cg * 32;
    __shared__ float    preA[GC][772], preB[GC][772];   // h@R pre-acts (scaled)
    __shared__ _Float16 hA[GC][264],  hB[GC][264];      // hidden states (f16)

    for (int i = tid; i < GC * 772; i += 512) { ((float*)preA)[i] = 0.f; ((float*)preB)[i] = 0.f; }
    for (int i = tid; i < GC * 264; i += 512) { ((_Float16*)hA)[i] = (_Float16)0.f; ((_Float16*)hB)[i] = (_Float16)0.f; }

    int mxA = 0, mxB = 0;
    #pragma unroll
    for (int i = 0; i < GC; i++) {
      mxA = max(mxA, lens_s[cbase + i]);
      mxB = max(mxB, lens_s[cbase + 16 + i]);
    }
    const int TL = max(mxA + NTICK, mxB + NTICK + 1);

    // R fragments, register-stationary, column-scaled (shared by A and B).
    half8 rfr[6][8];
    const int colw = wv * 96;
    #pragma unroll
    for (int tile = 0; tile < 6; tile++) {
      const int scol = colw + tile * 16;
      const float rsc = (scol < HH) ? SC_CI : SC_GT;
      const int col = scol + nl;
      #pragma unroll
      for (int kc = 0; kc < 8; kc++) {
        const int k0 = kc * 32 + quad * 8;
        half8 v;
        #pragma unroll
        for (int j = 0; j < 8; j++) v[j] = (_Float16)(R[(k0 + j) * (3 * HH) + col] * rsc);
        rfr[tile][kc] = v;
      }
    }

    // gate-thread identity: chain m, dim chunks {4*q32 + 128k}
    const int m   = tid >> 5;
    const int q32 = tid & 31;
    const int d0  = q32 * 4;
    const int lenA = lens_s[cbase + m];
    const int lenB = lens_s[cbase + 16 + m];
    const int chainA = cbase + m, chainB = cbase + 16 + m;

    float cstA[8], cstB[8];
    #pragma unroll
    for (int d = 0; d < 8; d++) { cstA[d] = 0.f; cstB[d] = 0.f; }

    const unsigned long long* rb = (const unsigned long long*)readyb;

    // ring prefetch helper: 6 u64 per thread for (time, chain)
    auto pf = [&](int time, int chain, unsigned long long* xw, int& cur, unsigned long long& rvn) {
      const int nc = time >> 2;
      if (nc != cur) {
        while (rvn != RDY8) rvn = sysload_u64(rb + nc);
        cur = nc;
        rvn = (nc + 1 < MAXCH) ? sysload_u64(rb + nc + 1) : RDY8;
      }
      asm volatile("" ::: "memory");
      const int slot = time & (DRING - 1);
      const unsigned long long* rp = ring + (((long)slot * BB + chain) * 192) + q32;
      xw[0] = sysload_u64(rp);       xw[1] = sysload_u64(rp + 32);
      xw[2] = sysload_u64(rp + 64);  xw[3] = sysload_u64(rp + 96);
      xw[4] = sysload_u64(rp + 128); xw[5] = sysload_u64(rp + 160);
    };

    // gate helper: time s, one group's chain m (scaled-exp2 LSTM body)
    auto gate_fn = [&](int s, int lenm, float* cst, float (*pre)[772],
                       _Float16 (*hsx)[264], const unsigned long long* xc, int chain) {
      const float* pr = &pre[m][0];
      #pragma unroll
      for (int k = 0; k < 2; k++) {
        const int dk = d0 + 128 * k;
        U64H4 uck, uik, uok;
        uck.u = xc[k]; uik.u = xc[2 + k]; uok.u = xc[4 + k];
        const f32x4 pci4 = *(const f32x4*)(pr + dk);
        const f32x4 pig4 = *(const f32x4*)(pr + 256 + dk);
        const f32x4 pog4 = *(const f32x4*)(pr + 512 + dk);
        float hh[4];
        #pragma unroll
        for (int r = 0; r < 4; r++) {
          const float pc = pci4[r] + (float)uck.h[r];
          const float pi = pig4[r] + (float)uik.h[r];
          const float po = pog4[r] + (float)uok.h[r];
          const float ea = fast_exp2(__builtin_fminf(pc, 43.0f));   // e^{2 pc}
          const float eb = fast_exp2(pi);                           // e^{-pi}
          const float t1 = __builtin_fmaf(ea, SC_CI, -SC_CI);
          const float cn = __builtin_fmaf(t1, fast_rcp((ea + 1.f) * (1.f + eb)), cst[k * 4 + r]);
          const float ec = fast_exp2(__builtin_fminf(cn, 43.0f));   // e^{2 c}
          const float ed = fast_exp2(po);                           // e^{-po}
          hh[r] = (ec - 1.f) * fast_rcp((ec + 1.f) * (1.f + ed));
          cst[k * 4 + r] = cn;
        }
        U64H4 up;
        up.p[0] = __builtin_amdgcn_cvt_pkrtz(hh[0], hh[1]);
        up.p[1] = __builtin_amdgcn_cvt_pkrtz(hh[2], hh[3]);
        *(unsigned long long*)(&hsx[m][dk]) = up.u;
        if (s == lenm + NTICK - 1) {
          float4 v; v.x = hh[0]; v.y = hh[1]; v.z = hh[2]; v.w = hh[3];
          *(float4*)(h_final + chain * HH + dk) = v;
        }
      }
    };

    // initial: wait chunk 0 ready, preload xwA(0); xwB filled in phase1 of t=0
    while (sysload_u64(rb + 0) != RDY8) {}
    asm volatile("" ::: "memory");
    unsigned long long xwA[6], xwB[6] = {0, 0, 0, 0, 0, 0};
    {
      const unsigned long long* rp = ring + ((long)chainA * 192) + q32;
      xwA[0] = sysload_u64(rp);       xwA[1] = sysload_u64(rp + 32);
      xwA[2] = sysload_u64(rp + 64);  xwA[3] = sysload_u64(rp + 96);
      xwA[4] = sysload_u64(rp + 128); xwA[5] = sysload_u64(rp + 160);
    }
    unsigned long long rvnA = sysload_u64(rb + 1);
    unsigned long long rvnB = sysload_u64(rb + 1);
    int curA = 0, curB = 0;
    __syncthreads();

    for (int t = 0; t < TL; ++t) {
      // ---------- PHASE 1: MFMA_A(t) || gate_B(t-1) ----------
      {
        f32x4 acc[6];
        #pragma unroll
        for (int i = 0; i < 6; i++) acc[i] = (f32x4){0.f, 0.f, 0.f, 0.f};
        if (t > 0) {
          const _Float16* hrow = &hA[nl][0];
          #pragma unroll
          for (int kc = 0; kc < 8; kc++) {
            const half8 a = *(const half8*)(hrow + kc * 32 + quad * 8);
            #pragma unroll
            for (int tile = 0; tile < 6; tile++)
              acc[tile] = __builtin_amdgcn_mfma_f32_16x16x32_f16(rfr[tile][kc], a, acc[tile], 0, 0, 0);
          }
        }
        unsigned long long xc[6];
        #pragma unroll
        for (int i = 0; i < 6; i++) xc[i] = xwB[i];          // vmcnt wait (loads 1 iter old)
        if (t < lenB + NTICK) pf(t, chainB, xwB, curB, rvnB); // issue B(t) early
        if (t >= 1 && t - 1 < lenB + NTICK)
          gate_fn(t - 1, lenB, cstB, preB, hB, xc, chainB);   // VALU/trans under MFMA shadow
        if (t > 0) {
          #pragma unroll
          for (int tile = 0; tile < 6; tile++)
            *(f32x4*)(&preA[nl][colw + tile * 16 + quad * 4]) = acc[tile];
        }
      }
      sync_lds_only();

      // ---------- PHASE 2: MFMA_B(t) || gate_A(t) ----------
      {
        f32x4 acc[6];
        #pragma unroll
        for (int i = 0; i < 6; i++) acc[i] = (f32x4){0.f, 0.f, 0.f, 0.f};
        if (t > 0) {
          const _Float16* hrow = &hB[nl][0];
          #pragma unroll
          for (int kc = 0; kc < 8; kc++) {
            const half8 a = *(const half8*)(hrow + kc * 32 + quad * 8);
            #pragma unroll
            for (int tile = 0; tile < 6; tile++)
              acc[tile] = __builtin_amdgcn_mfma_f32_16x16x32_f16(rfr[tile][kc], a, acc[tile], 0, 0, 0);
          }
        }
        unsigned long long xc[6];
        #pragma unroll
        for (int i = 0; i < 6; i++) xc[i] = xwA[i];
        if (t + 1 < lenA + NTICK) pf(t + 1, chainA, xwA, curA, rvnA);
        if (t < lenA + NTICK)
          gate_fn(t, lenA, cstA, preA, hA, xc, chainA);
        if (t > 0) {
          #pragma unroll
          for (int tile = 0; tile < 6; tile++)
            *(f32x4*)(&preB[nl][colw + tile * 16 + quad * 4]) = acc[tile];
        }
      }
      sync_lds_only();
      if (tid == 0) {
        sysstore_i32(prog + 2 * cg, t);
        sysstore_i32(prog + 2 * cg + 1, t - 1);
      }
    }
    if (tid == 0) {
      sysstore_i32(prog + 2 * cg, 1 << 20);
      sysstore_i32(prog + 2 * cg + 1, 1 << 20);
    }

  } else {
    // ======================= PRODUCER =======================
    const int pid = bx - NCG;       // 0..127
    const int s   = pid & 7;        // col slice (96 cols)
    const int pl  = pid >> 3;       // chunk lane 0..15

    int mxall = 0;
    #pragma unroll 8
    for (int i = 0; i < BB; i++) mxall = max(mxall, lens_s[i]);
    const int Tall = mxall + NTICK;
    const int nch  = (Tall + CH - 1) / CH;

    half8 wfr[4];
    float bias4[4], tick4[4];
    int col0w = 0;
    if (wv < 6) {
      col0w = s * 96 + wv * 16;
      const float wsc = (col0w < HH) ? SC_CI : SC_GT;
      #pragma unroll
      for (int kc = 0; kc < 4; kc++) {
        const int k0 = kc * 32 + quad * 8;
        half8 v;
        #pragma unroll
        for (int j = 0; j < 8; j++) v[j] = (_Float16)(W[(k0 + j) * (3 * HH) + col0w + nl] * wsc);
        wfr[kc] = v;
      }
      float4 b4 = *(const float4*)(bvec + col0w + quad * 4);
      float4 t4 = *(const float4*)(btk  + col0w + quad * 4);
      bias4[0] = b4.x * wsc; bias4[1] = b4.y * wsc; bias4[2] = b4.z * wsc; bias4[3] = b4.w * wsc;
      tick4[0] = t4.x * wsc; tick4[1] = t4.y * wsc; tick4[2] = t4.z * wsc; tick4[3] = t4.w * wsc;
    }

    for (int c = pl; c < nch; c += NPL) {
      if (c * CH >= DRING) {           // flow control: don't overwrite unread slots
        if (tid == 0) {
          const int need = c * CH + CH - DRING;
          for (;;) {
            int mn = 0x7fffffff;
            #pragma unroll
            for (int g = 0; g < NGRP; g++) mn = min(mn, sysload_i32(prog + g));
            if (mn >= need) break;
          }
        }
        __syncthreads();
      }
      if (wv < 6) {
        for (int tt = 0; tt < CH; tt++) {
          const int t = c * CH + tt;
          const int slot = t & (DRING - 1);
          #pragma unroll 2
          for (int bt = 0; bt < 8; bt++) {
            const int b = bt * 16 + nl;
            const int lenb = lens_s[b];
            f32x4 acc = {0.f, 0.f, 0.f, 0.f};
            if (t < LL) {
              const float* xp = x + ((long)b * LL + t) * FF + quad * 8;
              #pragma unroll
              for (int kc = 0; kc < 4; kc++) {
                const float4 u0 = *(const float4*)(xp + kc * 32);
                const float4 u1 = *(const float4*)(xp + kc * 32 + 4);
                half8 a;
                a[0] = (_Float16)u0.x; a[1] = (_Float16)u0.y;
                a[2] = (_Float16)u0.z; a[3] = (_Float16)u0.w;
                a[4] = (_Float16)u1.x; a[5] = (_Float16)u1.y;
                a[6] = (_Float16)u1.z; a[7] = (_Float16)u1.w;
                acc = __builtin_amdgcn_mfma_f32_16x16x32_f16(wfr[kc], a, acc, 0, 0, 0);
              }
            }
            U64H4 pk;
            const bool in_x  = (t < lenb);
            const bool in_tk = (t >= lenb) && (t < lenb + NTICK);
            #pragma unroll
            for (int r = 0; r < 4; r++) {
              float v = bias4[r];
              if (in_x)  v += acc[r];
              if (in_tk) v += tick4[r];
              pk.h[r] = (_Float16)v;
            }
            sysstore_u64(ring + ((((long)slot * BB + b) * 768 + col0w + quad * 4) >> 2), pk.u);
          }
        }
      }
      __syncthreads();   // vmcnt(0) before barrier => stores drained
      if (tid == 0) sysstore_u8(readyb + c * 8 + s, (unsigned char)1);
    }
  }
}

// out1 = h @ Wp^T + bp   (128x256)
extern "C" __global__ void proj_hp(const float* __restrict__ h,
                                   const float* __restrict__ Wp,
                                   const float* __restrict__ bp,
                                   float* __restrict__ hp)
{
  const int bb = blockIdx.x;
  const int j  = threadIdx.x;  // 256
  const float4* hv = (const float4*)(h + bb * HH);
  const float4* wr = (const float4*)(Wp + j * HH);
  float s = 0.f;
  for (int k = 0; k < HH / 4; k++) {
    const float4 a = hv[k], w = wr[k];
    s += a.x * w.x + a.y * w.y + a.z * w.z + a.w * w.w;
  }
  hp[bb * HH + j] = s + bp[j];
}

// out = hp @ Wo^T + bo   (128x128)
extern "C" __global__ void proj_out(const float* __restrict__ hp,
                                    const float* __restrict__ Wo,
                                    const float* __restrict__ bo,
                                    float* __restrict__ out)
{
  const int bb = blockIdx.x;
  const int o  = threadIdx.x;  // 128
  const float4* hv = (const float4*)(hp + bb * HH);
  const float4* wr = (const float4*)(Wo + o * HH);
  float s = 0.f;
  for (int k = 0; k < HH / 4; k++) {
    const float4 a = hv[k], w = wr[k];
    s += a.x * w.x + a.y * w.y + a.z * w.z + a.w * w.w;
  }
  out[bb * OO + o] = s + bo[o];
}

extern "C" void kernel_launch(void* const* d_in, const int* in_sizes, int n_in,
                              void* d_out, int out_size, void* d_ws, size_t ws_size,
                              hipStream_t stream)
{
  const float* x    = (const float*)d_in[0];
  const int*   ln   = (const int*)  d_in[1];
  const float* W    = (const float*)d_in[2];
  const float* R    = (const float*)d_in[3];
  const float* bvec = (const float*)d_in[4];
  const float* btk  = (const float*)d_in[5];
  const float* Wp   = (const float*)d_in[6];
  const float* bp   = (const float*)d_in[7];
  const float* Wo   = (const float*)d_in[8];
  const float* bo   = (const float*)d_in[9];
  float* out = (float*)d_out;

  // Workspace layout. No init pass needed:
  //   prog[] poisoned 0xAA..: negative => producers wait until consumers publish.
  //   readyb[] poisoned 0xAA != 1 => consumers wait until producers publish.
  char* ws = (char*)d_ws;
  int*                prog    = (int*)ws;                       // 32 B
  unsigned char*      readyb  = (unsigned char*)(ws + 64);      // MAXCH*8 = 4112 B
  float*              h_final = (float*)(ws + 8192);            // 128 KB
  float*              hp      = (float*)(ws + 8192 + 131072);   // 128 KB
  unsigned long long* ring    = (unsigned long long*)(ws + (1 << 20));  // 25.2 MB

  hipLaunchKernelGGL(lstm_all, dim3(NCG + NPS * NPL), dim3(512), 0, stream,
                     x, ln, W, R, bvec, btk, ring, readyb, prog, h_final);
  hipLaunchKernelGGL(proj_hp,  dim3(BB), dim3(HH), 0, stream, h_final, Wp, bp, hp);
  hipLaunchKernelGGL(proj_out, dim3(BB), dim3(OO), 0, stream, hp, Wo, bo, out);
}

// Round 9
// 17246.053 us; speedup vs baseline: 1.2389x; 1.2389x over previous
//
#include <hip/hip_runtime.h>

// Problem constants
#define BB    128   // batch
#define LL    2048  // seq len
#define FF    128   // input features
#define HH    256   // hidden
#define OO    128   // output
#define NTICK 5
#define GC    16    // chains per group
#define NGRP  8     // chain groups (prog[] entries)
#define NCG   4     // consumer blocks (2 groups each, phase-interleaved)
#define CH    4     // timesteps per ring chunk
#define DRING 128   // ring depth (timesteps)
#define NPS   8     // producer col-slices (96 cols each)
#define NPL   16    // producer chunk-lanes
#define MAXT  (LL + NTICK)
#define MAXCH ((MAXT + CH - 1) / CH)
#define RDY8  0x0101010101010101ULL

// Gate-column pre-scales folded into W/R/b/tick (bare v_exp_f32 in gate body):
//   ci cols: *2log2e ; ig/og cols: *-log2e.  c kept in ci-scaled units.
#define SC_CI  (2.8853900817779268f)
#define SC_GT  (-1.4426950408889634f)

typedef __attribute__((ext_vector_type(8))) _Float16 half8;
typedef __attribute__((ext_vector_type(2))) __fp16 fp16x2;
typedef __attribute__((ext_vector_type(4))) float f32x4;

union U64H4 { unsigned long long u; _Float16 h[4]; fp16x2 p[2]; };

__device__ __forceinline__ float fast_rcp(float x) { return __builtin_amdgcn_rcpf(x); }
__device__ __forceinline__ float fast_exp2(float x) { return __builtin_amdgcn_exp2f(x); }

__device__ __forceinline__ unsigned long long sysload_u64(const unsigned long long* p) {
  return __hip_atomic_load(p, __ATOMIC_RELAXED, __HIP_MEMORY_SCOPE_SYSTEM);
}
__device__ __forceinline__ void sysstore_u64(unsigned long long* p, unsigned long long v) {
  __hip_atomic_store(p, v, __ATOMIC_RELAXED, __HIP_MEMORY_SCOPE_SYSTEM);
}
__device__ __forceinline__ int sysload_i32(const int* p) {
  return __hip_atomic_load(p, __ATOMIC_RELAXED, __HIP_MEMORY_SCOPE_SYSTEM);
}
__device__ __forceinline__ void sysstore_i32(int* p, int v) {
  __hip_atomic_store(p, v, __ATOMIC_RELAXED, __HIP_MEMORY_SCOPE_SYSTEM);
}
__device__ __forceinline__ void sysstore_u8(unsigned char* p, unsigned char v) {
  __hip_atomic_store(p, v, __ATOMIC_RELAXED, __HIP_MEMORY_SCOPE_SYSTEM);
}

// Barrier with LDS-only drain: ring prefetch loads (vmcnt) stay in flight
// across the barrier; register dependency inserts the vmcnt wait at first use.
__device__ __forceinline__ void sync_lds_only() {
  asm volatile("s_waitcnt lgkmcnt(0)" ::: "memory");
  __builtin_amdgcn_s_barrier();
  asm volatile("" ::: "memory");
}

// --- MACROS, not lambdas: R8's lambda/pointer indirection let the register
// arrays' addresses escape -> scratch allocation (rule: addressable locals
// go to private memory) -> ~10k cyc/iter of serialized scratch latency.
// Textual substitution keeps xw*/cst*/cur*/rvn* in registers (R7-proven
// codegen pattern: plain arrays, compile-time indices only).

#define PF(timev, chain, xw, cur, rvn) do {                                     \
  const int nc_ = (timev) >> 2;                                                 \
  if (nc_ != (cur)) {                                                           \
    while ((rvn) != RDY8) (rvn) = sysload_u64(rb + nc_);                        \
    (cur) = nc_;                                                                \
    (rvn) = (nc_ + 1 < MAXCH) ? sysload_u64(rb + nc_ + 1) : RDY8;               \
  }                                                                             \
  asm volatile("" ::: "memory");                                                \
  const int slot_ = (timev) & (DRING - 1);                                      \
  const unsigned long long* rp_ = ring + (((long)slot_ * BB + (chain)) * 192) + q32; \
  xw[0] = sysload_u64(rp_);        xw[1] = sysload_u64(rp_ + 32);               \
  xw[2] = sysload_u64(rp_ + 64);   xw[3] = sysload_u64(rp_ + 96);               \
  xw[4] = sysload_u64(rp_ + 128);  xw[5] = sysload_u64(rp_ + 160);              \
} while (0)

// Scaled-exp2 LSTM gate body for 8 dims {4*q32 + 128k}.
#define GATE(sv, lenm, cst, pre, hsx, xc, chain) do {                           \
  const float* pr_ = &pre[m][0];                                                \
  _Pragma("unroll")                                                             \
  for (int k = 0; k < 2; k++) {                                                 \
    const int dk_ = d0 + 128 * k;                                               \
    U64H4 uck_, uik_, uok_;                                                     \
    uck_.u = xc[k]; uik_.u = xc[2 + k]; uok_.u = xc[4 + k];                     \
    const f32x4 pci4_ = *(const f32x4*)(pr_ + dk_);                             \
    const f32x4 pig4_ = *(const f32x4*)(pr_ + 256 + dk_);                       \
    const f32x4 pog4_ = *(const f32x4*)(pr_ + 512 + dk_);                       \
    float hh_[4];                                                               \
    _Pragma("unroll")                                                           \
    for (int r = 0; r < 4; r++) {                                               \
      const float pc_ = pci4_[r] + (float)uck_.h[r];                            \
      const float pi_ = pig4_[r] + (float)uik_.h[r];                            \
      const float po_ = pog4_[r] + (float)uok_.h[r];                            \
      const float ea_ = fast_exp2(__builtin_fminf(pc_, 43.0f));                 \
      const float eb_ = fast_exp2(pi_);                                         \
      const float t1_ = __builtin_fmaf(ea_, SC_CI, -SC_CI);                     \
      const float cn_ = __builtin_fmaf(t1_, fast_rcp((ea_ + 1.f) * (1.f + eb_)), cst[k * 4 + r]); \
      const float ec_ = fast_exp2(__builtin_fminf(cn_, 43.0f));                 \
      const float ed_ = fast_exp2(po_);                                         \
      hh_[r] = (ec_ - 1.f) * fast_rcp((ec_ + 1.f) * (1.f + ed_));               \
      cst[k * 4 + r] = cn_;                                                     \
    }                                                                           \
    U64H4 up_;                                                                  \
    up_.p[0] = __builtin_amdgcn_cvt_pkrtz(hh_[0], hh_[1]);                      \
    up_.p[1] = __builtin_amdgcn_cvt_pkrtz(hh_[2], hh_[3]);                      \
    *(unsigned long long*)(&hsx[m][dk_]) = up_.u;                               \
    if ((sv) == (lenm) + NTICK - 1) {                                           \
      float4 v_; v_.x = hh_[0]; v_.y = hh_[1]; v_.z = hh_[2]; v_.w = hh_[3];    \
      *(float4*)(h_final + (chain) * HH + dk_) = v_;                            \
    }                                                                           \
  }                                                                             \
} while (0)

#define MFMA6(hsx, acc) do {                                                    \
  const _Float16* hrow_ = &hsx[nl][0];                                          \
  _Pragma("unroll")                                                             \
  for (int kc = 0; kc < 8; kc++) {                                              \
    const half8 a_ = *(const half8*)(hrow_ + kc * 32 + quad * 8);               \
    _Pragma("unroll")                                                           \
    for (int tile = 0; tile < 6; tile++)                                        \
      acc[tile] = __builtin_amdgcn_mfma_f32_16x16x32_f16(rfr[tile][kc], a_, acc[tile], 0, 0, 0); \
  }                                                                             \
} while (0)

// Blocks 0..3: consumers. Each owns TWO independent 16-chain groups
// A (chains 32cg..+16) and B (+16), phase-interleaved so the MFMA pipe
// (group X's recurrent h@R) and the VALU/trans pipes (group Y's gates)
// overlap every phase instead of serializing:
//   phase1: MFMA_A(t) + gate_B(t-1)   | barrier
//   phase2: MFMA_B(t) + gate_A(t)     | barrier
// Blocks 4..131: producers (unchanged protocol; pre_x -> ring).
//
// MFMA layout: fragments loaded as B[k][n] (n=lane&15, k=quad*8+j); weight
// fragment in the A slot => lane nl reg r = pre[chain=nl][col=base+quad*4+r].
// Gate thread (m=tid>>5, q32=tid&31) owns dims {4*q32+128k}, bank-balanced.
extern "C" __global__ __launch_bounds__(512, 1)
void lstm_all(const float* __restrict__ x, const int* __restrict__ lens,
              const float* __restrict__ W, const float* __restrict__ R,
              const float* __restrict__ bvec, const float* __restrict__ btk,
              unsigned long long* ring, unsigned char* readyb,
              int* prog, float* __restrict__ h_final)
{
  const int tid  = threadIdx.x;
  const int lane = tid & 63;
  const int wv   = tid >> 6;
  const int quad = lane >> 4;
  const int nl   = lane & 15;
  const int bx   = blockIdx.x;

  __shared__ int lens_s[BB];
  if (tid < BB) lens_s[tid] = lens[tid];
  __syncthreads();

  if (bx < NCG) {
    // ======================= CONSUMER =======================
    const int cg = bx, cbase = cg * 32;
    __shared__ float    preA[GC][772], preB[GC][772];   // h@R pre-acts (scaled)
    __shared__ _Float16 hA[GC][264],  hB[GC][264];      // hidden states (f16)

    for (int i = tid; i < GC * 772; i += 512) { ((float*)preA)[i] = 0.f; ((float*)preB)[i] = 0.f; }
    for (int i = tid; i < GC * 264; i += 512) { ((_Float16*)hA)[i] = (_Float16)0.f; ((_Float16*)hB)[i] = (_Float16)0.f; }

    int mxA = 0, mxB = 0;
    #pragma unroll
    for (int i = 0; i < GC; i++) {
      mxA = max(mxA, lens_s[cbase + i]);
      mxB = max(mxB, lens_s[cbase + 16 + i]);
    }
    const int TL = max(mxA + NTICK, mxB + NTICK + 1);

    // R fragments, register-stationary, column-scaled (shared by A and B).
    half8 rfr[6][8];
    const int colw = wv * 96;
    #pragma unroll
    for (int tile = 0; tile < 6; tile++) {
      const int scol = colw + tile * 16;
      const float rsc = (scol < HH) ? SC_CI : SC_GT;
      const int col = scol + nl;
      #pragma unroll
      for (int kc = 0; kc < 8; kc++) {
        const int k0 = kc * 32 + quad * 8;
        half8 v;
        #pragma unroll
        for (int j = 0; j < 8; j++) v[j] = (_Float16)(R[(k0 + j) * (3 * HH) + col] * rsc);
        rfr[tile][kc] = v;
      }
    }

    // gate-thread identity: chain m, dim chunks {4*q32 + 128k}
    const int m   = tid >> 5;
    const int q32 = tid & 31;
    const int d0  = q32 * 4;
    const int lenA = lens_s[cbase + m];
    const int lenB = lens_s[cbase + 16 + m];
    const int chainA = cbase + m, chainB = cbase + 16 + m;

    float cstA[8], cstB[8];
    #pragma unroll
    for (int d = 0; d < 8; d++) { cstA[d] = 0.f; cstB[d] = 0.f; }

    const unsigned long long* rb = (const unsigned long long*)readyb;

    // initial: wait chunk 0 ready, preload xwA(0); xwB filled in phase1 of t=0
    while (sysload_u64(rb + 0) != RDY8) {}
    asm volatile("" ::: "memory");
    unsigned long long xwA[6], xwB[6] = {0, 0, 0, 0, 0, 0};
    {
      const unsigned long long* rp = ring + ((long)chainA * 192) + q32;
      xwA[0] = sysload_u64(rp);       xwA[1] = sysload_u64(rp + 32);
      xwA[2] = sysload_u64(rp + 64);  xwA[3] = sysload_u64(rp + 96);
      xwA[4] = sysload_u64(rp + 128); xwA[5] = sysload_u64(rp + 160);
    }
    unsigned long long rvnA = sysload_u64(rb + 1);
    unsigned long long rvnB = sysload_u64(rb + 1);
    int curA = 0, curB = 0;
    __syncthreads();

    for (int t = 0; t < TL; ++t) {
      // ---------- PHASE 1: MFMA_A(t) || gate_B(t-1) ----------
      {
        f32x4 acc[6];
        #pragma unroll
        for (int i = 0; i < 6; i++) acc[i] = (f32x4){0.f, 0.f, 0.f, 0.f};
        if (t > 0) MFMA6(hA, acc);
        unsigned long long xc[6];
        #pragma unroll
        for (int i = 0; i < 6; i++) xc[i] = xwB[i];   // B(t-1), loaded 1 iter ago
        if (t < lenB + NTICK) PF(t, chainB, xwB, curB, rvnB);
        if (t >= 1 && t - 1 < lenB + NTICK) GATE(t - 1, lenB, cstB, preB, hB, xc, chainB);
        if (t > 0) {
          #pragma unroll
          for (int tile = 0; tile < 6; tile++)
            *(f32x4*)(&preA[nl][colw + tile * 16 + quad * 4]) = acc[tile];
        }
      }
      sync_lds_only();

      // ---------- PHASE 2: MFMA_B(t) || gate_A(t) ----------
      {
        f32x4 acc[6];
        #pragma unroll
        for (int i = 0; i < 6; i++) acc[i] = (f32x4){0.f, 0.f, 0.f, 0.f};
        if (t > 0) MFMA6(hB, acc);
        unsigned long long xc[6];
        #pragma unroll
        for (int i = 0; i < 6; i++) xc[i] = xwA[i];   // A(t), loaded 1 iter ago
        if (t + 1 < lenA + NTICK) PF(t + 1, chainA, xwA, curA, rvnA);
        if (t < lenA + NTICK) GATE(t, lenA, cstA, preA, hA, xc, chainA);
        if (t > 0) {
          #pragma unroll
          for (int tile = 0; tile < 6; tile++)
            *(f32x4*)(&preB[nl][colw + tile * 16 + quad * 4]) = acc[tile];
        }
      }
      sync_lds_only();
      if (tid == 0) {
        sysstore_i32(prog + 2 * cg, t);
        sysstore_i32(prog + 2 * cg + 1, t - 1);
      }
    }
    if (tid == 0) {
      sysstore_i32(prog + 2 * cg, 1 << 20);
      sysstore_i32(prog + 2 * cg + 1, 1 << 20);
    }

  } else {
    // ======================= PRODUCER =======================
    const int pid = bx - NCG;       // 0..127
    const int s   = pid & 7;        // col slice (96 cols)
    const int pl  = pid >> 3;       // chunk lane 0..15

    int mxall = 0;
    #pragma unroll 8
    for (int i = 0; i < BB; i++) mxall = max(mxall, lens_s[i]);
    const int Tall = mxall + NTICK;
    const int nch  = (Tall + CH - 1) / CH;

    half8 wfr[4];
    float bias4[4], tick4[4];
    int col0w = 0;
    if (wv < 6) {
      col0w = s * 96 + wv * 16;
      const float wsc = (col0w < HH) ? SC_CI : SC_GT;
      #pragma unroll
      for (int kc = 0; kc < 4; kc++) {
        const int k0 = kc * 32 + quad * 8;
        half8 v;
        #pragma unroll
        for (int j = 0; j < 8; j++) v[j] = (_Float16)(W[(k0 + j) * (3 * HH) + col0w + nl] * wsc);
        wfr[kc] = v;
      }
      float4 b4 = *(const float4*)(bvec + col0w + quad * 4);
      float4 t4 = *(const float4*)(btk  + col0w + quad * 4);
      bias4[0] = b4.x * wsc; bias4[1] = b4.y * wsc; bias4[2] = b4.z * wsc; bias4[3] = b4.w * wsc;
      tick4[0] = t4.x * wsc; tick4[1] = t4.y * wsc; tick4[2] = t4.z * wsc; tick4[3] = t4.w * wsc;
    }

    for (int c = pl; c < nch; c += NPL) {
      if (c * CH >= DRING) {           // flow control: don't overwrite unread slots
        if (tid == 0) {
          const int need = c * CH + CH - DRING;
          for (;;) {
            int mn = 0x7fffffff;
            #pragma unroll
            for (int g = 0; g < NGRP; g++) mn = min(mn, sysload_i32(prog + g));
            if (mn >= need) break;
          }
        }
        __syncthreads();
      }
      if (wv < 6) {
        for (int tt = 0; tt < CH; tt++) {
          const int t = c * CH + tt;
          const int slot = t & (DRING - 1);
          #pragma unroll 2
          for (int bt = 0; bt < 8; bt++) {
            const int b = bt * 16 + nl;
            const int lenb = lens_s[b];
            f32x4 acc = {0.f, 0.f, 0.f, 0.f};
            if (t < LL) {
              const float* xp = x + ((long)b * LL + t) * FF + quad * 8;
              #pragma unroll
              for (int kc = 0; kc < 4; kc++) {
                const float4 u0 = *(const float4*)(xp + kc * 32);
                const float4 u1 = *(const float4*)(xp + kc * 32 + 4);
                half8 a;
                a[0] = (_Float16)u0.x; a[1] = (_Float16)u0.y;
                a[2] = (_Float16)u0.z; a[3] = (_Float16)u0.w;
                a[4] = (_Float16)u1.x; a[5] = (_Float16)u1.y;
                a[6] = (_Float16)u1.z; a[7] = (_Float16)u1.w;
                acc = __builtin_amdgcn_mfma_f32_16x16x32_f16(wfr[kc], a, acc, 0, 0, 0);
              }
            }
            U64H4 pk;
            const bool in_x  = (t < lenb);
            const bool in_tk = (t >= lenb) && (t < lenb + NTICK);
            #pragma unroll
            for (int r = 0; r < 4; r++) {
              float v = bias4[r];
              if (in_x)  v += acc[r];
              if (in_tk) v += tick4[r];
              pk.h[r] = (_Float16)v;
            }
            sysstore_u64(ring + ((((long)slot * BB + b) * 768 + col0w + quad * 4) >> 2), pk.u);
          }
        }
      }
      __syncthreads();   // vmcnt(0) before barrier => stores drained
      if (tid == 0) sysstore_u8(readyb + c * 8 + s, (unsigned char)1);
    }
  }
}

// out1 = h @ Wp^T + bp   (128x256)
extern "C" __global__ void proj_hp(const float* __restrict__ h,
                                   const float* __restrict__ Wp,
                                   const float* __restrict__ bp,
                                   float* __restrict__ hp)
{
  const int bb = blockIdx.x;
  const int j  = threadIdx.x;  // 256
  const float4* hv = (const float4*)(h + bb * HH);
  const float4* wr = (const float4*)(Wp + j * HH);
  float s = 0.f;
  for (int k = 0; k < HH / 4; k++) {
    const float4 a = hv[k], w = wr[k];
    s += a.x * w.x + a.y * w.y + a.z * w.z + a.w * w.w;
  }
  hp[bb * HH + j] = s + bp[j];
}

// out = hp @ Wo^T + bo   (128x128)
extern "C" __global__ void proj_out(const float* __restrict__ hp,
                                    const float* __restrict__ Wo,
                                    const float* __restrict__ bo,
                                    float* __restrict__ out)
{
  const int bb = blockIdx.x;
  const int o  = threadIdx.x;  // 128
  const float4* hv = (const float4*)(hp + bb * HH);
  const float4* wr = (const float4*)(Wo + o * HH);
  float s = 0.f;
  for (int k = 0; k < HH / 4; k++) {
    const float4 a = hv[k], w = wr[k];
    s += a.x * w.x + a.y * w.y + a.z * w.z + a.w * w.w;
  }
  out[bb * OO + o] = s + bo[o];
}

extern "C" void kernel_launch(void* const* d_in, const int* in_sizes, int n_in,
                              void* d_out, int out_size, void* d_ws, size_t ws_size,
                              hipStream_t stream)
{
  const float* x    = (const float*)d_in[0];
  const int*   ln   = (const int*)  d_in[1];
  const float* W    = (const float*)d_in[2];
  const float* R    = (const float*)d_in[3];
  const float* bvec = (const float*)d_in[4];
  const float* btk  = (const float*)d_in[5];
  const float* Wp   = (const float*)d_in[6];
  const float* bp   = (const float*)d_in[7];
  const float* Wo   = (const float*)d_in[8];
  const float* bo   = (const float*)d_in[9];
  float* out = (float*)d_out;

  // Workspace layout. No init pass needed:
  //   prog[] poisoned 0xAA..: negative => producers wait until consumers publish.
  //   readyb[] poisoned 0xAA != 1 => consumers wait until producers publish.
  char* ws = (char*)d_ws;
  int*                prog    = (int*)ws;                       // 32 B
  unsigned char*      readyb  = (unsigned char*)(ws + 64);      // MAXCH*8 = 4112 B
  float*              h_final = (float*)(ws + 8192);            // 128 KB
  float*              hp      = (float*)(ws + 8192 + 131072);   // 128 KB
  unsigned long long* ring    = (unsigned long long*)(ws + (1 << 20));  // 25.2 MB

  hipLaunchKernelGGL(lstm_all, dim3(NCG + NPS * NPL), dim3(512), 0, stream,
                     x, ln, W, R, bvec, btk, ring, readyb, prog, h_final);
  hipLaunchKernelGGL(proj_hp,  dim3(BB), dim3(HH), 0, stream, h_final, Wp, bp, hp);
  hipLaunchKernelGGL(proj_out, dim3(BB), dim3(OO), 0, stream, hp, Wo, bo, out);
}

// Round 10
// 5875.344 us; speedup vs baseline: 3.6365x; 2.9353x over previous
//
#include <hip/hip_runtime.h>

// Problem constants
#define BB    128   // batch
#define LL    2048  // seq len
#define FF    128   // input features
#define HH    256   // hidden
#define OO    128   // output
#define NTICK 5
#define GC    16    // chains per consumer group
#define NCG   8     // consumer groups (blocks 0..7)
#define CH    4     // timesteps per ring chunk
#define DRING 128   // ring depth (timesteps)
#define NPS   8     // producer col-slices (96 cols each)
#define NPL   16    // producer chunk-lanes
#define MAXT  (LL + NTICK)
#define MAXCH ((MAXT + CH - 1) / CH)
#define RDY8  0x0101010101010101ULL

// Gate-column pre-scales folded into W/R/b/tick (bare v_exp_f32 in gate body):
//   ci cols: *2log2e ; ig/og cols: *-log2e.  c kept in ci-scaled units.
#define SC_CI  (2.8853900817779268f)
#define SC_GT  (-1.4426950408889634f)

typedef __attribute__((ext_vector_type(8))) _Float16 half8;
typedef __attribute__((ext_vector_type(2))) __fp16 fp16x2;
typedef __attribute__((ext_vector_type(4))) float f32x4;

union U64H4 { unsigned long long u; _Float16 h[4]; fp16x2 p[2]; };

__device__ __forceinline__ float fast_rcp(float x) { return __builtin_amdgcn_rcpf(x); }
__device__ __forceinline__ float fast_exp2(float x) { return __builtin_amdgcn_exp2f(x); }

__device__ __forceinline__ unsigned long long sysload_u64(const unsigned long long* p) {
  return __hip_atomic_load(p, __ATOMIC_RELAXED, __HIP_MEMORY_SCOPE_SYSTEM);
}
__device__ __forceinline__ void sysstore_u64(unsigned long long* p, unsigned long long v) {
  __hip_atomic_store(p, v, __ATOMIC_RELAXED, __HIP_MEMORY_SCOPE_SYSTEM);
}
__device__ __forceinline__ int sysload_i32(const int* p) {
  return __hip_atomic_load(p, __ATOMIC_RELAXED, __HIP_MEMORY_SCOPE_SYSTEM);
}
__device__ __forceinline__ void sysstore_i32(int* p, int v) {
  __hip_atomic_store(p, v, __ATOMIC_RELAXED, __HIP_MEMORY_SCOPE_SYSTEM);
}
__device__ __forceinline__ void sysstore_u8(unsigned char* p, unsigned char v) {
  __hip_atomic_store(p, v, __ATOMIC_RELAXED, __HIP_MEMORY_SCOPE_SYSTEM);
}

// Barrier with LDS-only drain: ring prefetch loads (vmcnt) stay in flight
// across the barrier; register dependency inserts the vmcnt wait at first use.
__device__ __forceinline__ void sync_lds_only() {
  asm volatile("s_waitcnt lgkmcnt(0)" ::: "memory");
  __builtin_amdgcn_s_barrier();
  asm volatile("" ::: "memory");
}

// Blocks 0..7: consumers (16 chains per block, 8 waves; R register-stationary).
// Blocks 8..135: producers (col-slice s = pid&7, chunk-lane = pid>>3).
//
// REGISTER BUDGET (the R0..R9 bug): consumer wave state = rfr 192 VGPR
// (6 tiles x 8 kc x half8) + acc/gate/prefetch ~60 = ~252. With
// __launch_bounds__(512,1) the backend capped allocation at 128 VGPRs
// (occupancy heuristic) -> ~124 regs incl. the R fragments spilled to
// scratch, re-read 48x per step => the kernel was scratch-BW-bound
// (explains: step ~6100cy vs ~2000cy issue floor; conflict/exp/prefetch
// fixes all <5%; R8/R9's +30 live regs => 3x collapse).
// Fix: 2nd launch_bounds arg = MIN WAVES PER EU = 2 -> VGPR cap 256 ->
// rfr register-resident. We run 1 block/CU = 2 waves/SIMD either way,
// so no occupancy change.
extern "C" __global__ __launch_bounds__(512, 2)
void lstm_all(const float* __restrict__ x, const int* __restrict__ lens,
              const float* __restrict__ W, const float* __restrict__ R,
              const float* __restrict__ bvec, const float* __restrict__ btk,
              unsigned long long* ring, unsigned char* readyb,
              int* prog, float* __restrict__ h_final)
{
  const int tid  = threadIdx.x;
  const int lane = tid & 63;
  const int wv   = tid >> 6;
  const int quad = lane >> 4;
  const int nl   = lane & 15;
  const int bx   = blockIdx.x;

  __shared__ int lens_s[BB];
  if (tid < BB) lens_s[tid] = lens[tid];
  __syncthreads();

  if (bx < NCG) {
    // ======================= CONSUMER =======================
    const int cg = bx, cbase = cg * GC;
    __shared__ float    pre_s[GC][772];   // h@R pre-activations, fp32 (scaled units)
    __shared__ _Float16 h_s[GC][264];     // hidden state (f16, true units)

    for (int i = tid; i < GC * 772; i += 512) ((float*)pre_s)[i] = 0.f;
    for (int i = tid; i < GC * 264; i += 512) ((_Float16*)h_s)[i] = (_Float16)0.f;

    int mxl = 0;
    #pragma unroll
    for (int i = 0; i < GC; i++) mxl = max(mxl, lens_s[cbase + i]);
    const int Tg = mxl + NTICK;

    // R fragments, register-stationary, column-scaled. Wave wv owns cols
    // [wv*96, wv*96+96): loaded as B[k][n]: n = lane&15, k = quad*8+j.
    half8 rfr[6][8];
    const int colw = wv * 96;
    #pragma unroll
    for (int tile = 0; tile < 6; tile++) {
      const int scol = colw + tile * 16;
      const float rsc = (scol < HH) ? SC_CI : SC_GT;
      const int col = scol + nl;
      #pragma unroll
      for (int kc = 0; kc < 8; kc++) {
        const int k0 = kc * 32 + quad * 8;
        half8 v;
        #pragma unroll
        for (int j = 0; j < 8; j++) v[j] = (_Float16)(R[(k0 + j) * (3 * HH) + col] * rsc);
        rfr[tile][kc] = v;
      }
    }

    // gate-thread identity: chain m, dim chunks {4*q32 + 128k}
    const int m   = tid >> 5;
    const int q32 = tid & 31;
    const int d0  = q32 * 4;
    const int lenm = lens_s[cbase + m];

    // cell state: thread-private registers (ci-scaled units); [k*4 + r]
    float cst[8];
    #pragma unroll
    for (int d = 0; d < 8; d++) cst[d] = 0.f;

    const unsigned long long* rb = (const unsigned long long*)readyb;

    // initial: wait chunk 0, prefetch xw(0).
    // xw[g*2+k] = ring u64 at chain-row + 64g + 32k + q32  (col = 256g+128k+d0)
    while (sysload_u64(rb + 0) != RDY8) {}
    asm volatile("" ::: "memory");
    unsigned long long xw[6];
    {
      const unsigned long long* rp = ring + (((long)0 * BB + cbase + m) * 192) + q32;
      xw[0] = sysload_u64(rp);       xw[1] = sysload_u64(rp + 32);
      xw[2] = sysload_u64(rp + 64);  xw[3] = sysload_u64(rp + 96);
      xw[4] = sysload_u64(rp + 128); xw[5] = sysload_u64(rp + 160);
    }
    unsigned long long rvn = sysload_u64(rb + 1);
    int cur_chunk = 0;
    __syncthreads();

    for (int t = 0; t < Tg; ++t) {
      // ---- recurrent MFMA phase: pre_h = h(t-1) @ R
      if (t > 0) {
        f32x4 acc[6];
        #pragma unroll
        for (int i = 0; i < 6; i++) acc[i] = (f32x4){0.f, 0.f, 0.f, 0.f};
        const _Float16* hrow = &h_s[nl][0];
        #pragma unroll
        for (int kc = 0; kc < 8; kc++) {
          const half8 a = *(const half8*)(hrow + kc * 32 + quad * 8);
          #pragma unroll
          for (int tile = 0; tile < 6; tile++)
            acc[tile] = __builtin_amdgcn_mfma_f32_16x16x32_f16(rfr[tile][kc], a, acc[tile], 0, 0, 0);
        }
        // spill: lane nl reg r = pre[chain=nl][colw+tile*16+quad*4+r]
        #pragma unroll
        for (int tile = 0; tile < 6; tile++)
          *(f32x4*)(&pre_s[nl][colw + tile * 16 + quad * 4]) = acc[tile];
      }
      sync_lds_only();   // pre_s(t) visible; prior ring loads NOT drained here

      // ---- capture xw(t), then issue prefetch xw(t+1) EARLY so its latency
      // hides under the gate phase + next MFMA phase (no vmcnt drain at barriers)
      unsigned long long xwc[6];
      #pragma unroll
      for (int i = 0; i < 6; i++) xwc[i] = xw[i];

      if (t + 1 < Tg && t + 1 < lenm + NTICK) {
        const int nc = (t + 1) >> 2;
        if (nc != cur_chunk) {
          while (rvn != RDY8) rvn = sysload_u64(rb + nc);
          cur_chunk = nc;
          rvn = (nc + 1 < MAXCH) ? sysload_u64(rb + nc + 1) : RDY8;
        }
        asm volatile("" ::: "memory");
        const int slot = (t + 1) & (DRING - 1);
        const unsigned long long* rp = ring + (((long)slot * BB + cbase + m) * 192) + q32;
        xw[0] = sysload_u64(rp);       xw[1] = sysload_u64(rp + 32);
        xw[2] = sysload_u64(rp + 64);  xw[3] = sysload_u64(rp + 96);
        xw[4] = sysload_u64(rp + 128); xw[5] = sysload_u64(rp + 160);
      }

      // ---- gate phase (per-thread; execz-skipped when whole wave frozen)
      if (t < lenm + NTICK) {
        const float* pr = &pre_s[m][0];
        #pragma unroll
        for (int k = 0; k < 2; k++) {
          const int dk = d0 + 128 * k;
          U64H4 uck, uik, uok;
          uck.u = xwc[k];     // ci cols
          uik.u = xwc[2 + k]; // ig cols
          uok.u = xwc[4 + k]; // og cols
          const f32x4 pci4 = *(const f32x4*)(pr + dk);
          const f32x4 pig4 = *(const f32x4*)(pr + 256 + dk);
          const f32x4 pog4 = *(const f32x4*)(pr + 512 + dk);
          float hh[4];
          #pragma unroll
          for (int r = 0; r < 4; r++) {
            // scaled units: pc = 2log2e*pc_true, pi = -log2e*pi_true, po = -log2e*po_true
            const float pc = pci4[r] + (float)uck.h[r];
            const float pi = pig4[r] + (float)uik.h[r];
            const float po = pog4[r] + (float)uok.h[r];
            // dc = tanh(pc)*sigmoid(pi) = (e^{2pc}-1) / ((e^{2pc}+1)(1+e^{-pi}))
            const float ea = fast_exp2(__builtin_fminf(pc, 43.0f));   // e^{2 pc_true}
            const float eb = fast_exp2(pi);                           // e^{-pi_true}
            const float t1 = __builtin_fmaf(ea, SC_CI, -SC_CI);       // 2log2e*(ea-1)
            const float cn = __builtin_fmaf(t1, fast_rcp((ea + 1.f) * (1.f + eb)), cst[k * 4 + r]);
            const float ec = fast_exp2(__builtin_fminf(cn, 43.0f));   // e^{2 c_true}
            const float ed = fast_exp2(po);                           // e^{-po_true}
            hh[r] = (ec - 1.f) * fast_rcp((ec + 1.f) * (1.f + ed));
            cst[k * 4 + r] = cn;
          }
          U64H4 up;
          up.p[0] = __builtin_amdgcn_cvt_pkrtz(hh[0], hh[1]);
          up.p[1] = __builtin_amdgcn_cvt_pkrtz(hh[2], hh[3]);
          *(unsigned long long*)(&h_s[m][dk]) = up.u;
          if (t == lenm + NTICK - 1) {
            float4 v; v.x = hh[0]; v.y = hh[1]; v.z = hh[2]; v.w = hh[3];
            *(float4*)(h_final + (cbase + m) * HH + dk) = v;
          }
        }
      }

      sync_lds_only();   // h_s(t) visible; ring prefetch stays in flight
      if (tid == 0) sysstore_i32(prog + cg, t);
    }
    if (tid == 0) sysstore_i32(prog + cg, 1 << 20);

  } else {
    // ======================= PRODUCER =======================
    const int pid = bx - NCG;       // 0..127
    const int s   = pid & 7;        // col slice (96 cols)
    const int pl  = pid >> 3;       // chunk lane 0..15

    int mxall = 0;
    #pragma unroll 8
    for (int i = 0; i < BB; i++) mxall = max(mxall, lens_s[i]);
    const int Tall = mxall + NTICK;
    const int nch  = (Tall + CH - 1) / CH;

    half8 wfr[4];
    float bias4[4], tick4[4];
    int col0w = 0;
    if (wv < 6) {
      col0w = s * 96 + wv * 16;
      const float wsc = (col0w < HH) ? SC_CI : SC_GT;   // whole 16-col tile same gate
      #pragma unroll
      for (int kc = 0; kc < 4; kc++) {
        const int k0 = kc * 32 + quad * 8;
        half8 v;
        #pragma unroll
        for (int j = 0; j < 8; j++) v[j] = (_Float16)(W[(k0 + j) * (3 * HH) + col0w + nl] * wsc);
        wfr[kc] = v;
      }
      float4 b4 = *(const float4*)(bvec + col0w + quad * 4);
      float4 t4 = *(const float4*)(btk  + col0w + quad * 4);
      bias4[0] = b4.x * wsc; bias4[1] = b4.y * wsc; bias4[2] = b4.z * wsc; bias4[3] = b4.w * wsc;
      tick4[0] = t4.x * wsc; tick4[1] = t4.y * wsc; tick4[2] = t4.z * wsc; tick4[3] = t4.w * wsc;
    }

    for (int c = pl; c < nch; c += NPL) {
      if (c * CH >= DRING) {           // flow control: don't overwrite unread slots
        if (tid == 0) {
          const int need = c * CH + CH - DRING;
          for (;;) {
            int mn = 0x7fffffff;
            #pragma unroll
            for (int g = 0; g < NCG; g++) mn = min(mn, sysload_i32(prog + g));
            if (mn >= need) break;
          }
        }
        __syncthreads();
      }
      if (wv < 6) {
        for (int tt = 0; tt < CH; tt++) {
          const int t = c * CH + tt;
          const int slot = t & (DRING - 1);
          #pragma unroll 2
          for (int bt = 0; bt < 8; bt++) {
            const int b = bt * 16 + nl;
            const int lenb = lens_s[b];
            f32x4 acc = {0.f, 0.f, 0.f, 0.f};
            if (t < LL) {
              const float* xp = x + ((long)b * LL + t) * FF + quad * 8;
              #pragma unroll
              for (int kc = 0; kc < 4; kc++) {
                const float4 u0 = *(const float4*)(xp + kc * 32);
                const float4 u1 = *(const float4*)(xp + kc * 32 + 4);
                half8 a;
                a[0] = (_Float16)u0.x; a[1] = (_Float16)u0.y;
                a[2] = (_Float16)u0.z; a[3] = (_Float16)u0.w;
                a[4] = (_Float16)u1.x; a[5] = (_Float16)u1.y;
                a[6] = (_Float16)u1.z; a[7] = (_Float16)u1.w;
                // W-frag in A slot, x-frag in B slot:
                // lane nl reg r = pre_x[batch=bt*16+nl][col0w+quad*4+r]
                acc = __builtin_amdgcn_mfma_f32_16x16x32_f16(wfr[kc], a, acc, 0, 0, 0);
              }
            }
            U64H4 pk;
            const bool in_x  = (t < lenb);
            const bool in_tk = (t >= lenb) && (t < lenb + NTICK);
            #pragma unroll
            for (int r = 0; r < 4; r++) {
              float v = bias4[r];
              if (in_x)  v += acc[r];
              if (in_tk) v += tick4[r];
              pk.h[r] = (_Float16)v;
            }
            sysstore_u64(ring + ((((long)slot * BB + b) * 768 + col0w + quad * 4) >> 2), pk.u);
          }
        }
      }
      __syncthreads();   // vmcnt(0) before barrier => stores drained
      if (tid == 0) sysstore_u8(readyb + c * 8 + s, (unsigned char)1);
    }
  }
}

// out1 = h @ Wp^T + bp   (128x256)
extern "C" __global__ void proj_hp(const float* __restrict__ h,
                                   const float* __restrict__ Wp,
                                   const float* __restrict__ bp,
                                   float* __restrict__ hp)
{
  const int bb = blockIdx.x;
  const int j  = threadIdx.x;  // 256
  const float4* hv = (const float4*)(h + bb * HH);
  const float4* wr = (const float4*)(Wp + j * HH);
  float s = 0.f;
  for (int k = 0; k < HH / 4; k++) {
    const float4 a = hv[k], w = wr[k];
    s += a.x * w.x + a.y * w.y + a.z * w.z + a.w * w.w;
  }
  hp[bb * HH + j] = s + bp[j];
}

// out = hp @ Wo^T + bo   (128x128)
extern "C" __global__ void proj_out(const float* __restrict__ hp,
                                    const float* __restrict__ Wo,
                                    const float* __restrict__ bo,
                                    float* __restrict__ out)
{
  const int bb = blockIdx.x;
  const int o  = threadIdx.x;  // 128
  const float4* hv = (const float4*)(hp + bb * HH);
  const float4* wr = (const float4*)(Wo + o * HH);
  float s = 0.f;
  for (int k = 0; k < HH / 4; k++) {
    const float4 a = hv[k], w = wr[k];
    s += a.x * w.x + a.y * w.y + a.z * w.z + a.w * w.w;
  }
  out[bb * OO + o] = s + bo[o];
}

extern "C" void kernel_launch(void* const* d_in, const int* in_sizes, int n_in,
                              void* d_out, int out_size, void* d_ws, size_t ws_size,
                              hipStream_t stream)
{
  const float* x    = (const float*)d_in[0];
  const int*   ln   = (const int*)  d_in[1];
  const float* W    = (const float*)d_in[2];
  const float* R    = (const float*)d_in[3];
  const float* bvec = (const float*)d_in[4];
  const float* btk  = (const float*)d_in[5];
  const float* Wp   = (const float*)d_in[6];
  const float* bp   = (const float*)d_in[7];
  const float* Wo   = (const float*)d_in[8];
  const float* bo   = (const float*)d_in[9];
  float* out = (float*)d_out;

  // Workspace layout. No init pass needed:
  //   prog[] poisoned 0xAA..: negative => producers wait until consumers publish.
  //   readyb[] poisoned 0xAA != 1 => consumers wait until producers publish.
  char* ws = (char*)d_ws;
  int*                prog    = (int*)ws;                       // 32 B
  unsigned char*      readyb  = (unsigned char*)(ws + 64);      // MAXCH*8 = 4112 B
  float*              h_final = (float*)(ws + 8192);            // 128 KB
  float*              hp      = (float*)(ws + 8192 + 131072);   // 128 KB
  unsigned long long* ring    = (unsigned long long*)(ws + (1 << 20));  // 25.2 MB

  hipLaunchKernelGGL(lstm_all, dim3(NCG + NPS * NPL), dim3(512), 0, stream,
                     x, ln, W, R, bvec, btk, ring, readyb, prog, h_final);
  hipLaunchKernelGGL(proj_hp,  dim3(BB), dim3(HH), 0, stream, h_final, Wp, bp, hp);
  hipLaunchKernelGGL(proj_out, dim3(BB), dim3(OO), 0, stream, hp, Wo, bo, out);
}